// Round 14
// baseline (294.130 us; speedup 1.0000x reference)
//
#include <hip/hip_runtime.h>
#include <hip/hip_bf16.h>

#define N_NODES 50000
#define N_REL 4
#define N_EDGES 400000
#define CHUNK 1024
#define NCHUNK ((N_NODES + CHUNK - 1) / CHUNK)  // 49

#define EB 32                 // edge chunks per relation
#define ECH (N_EDGES / EB)    // 12500 edges per chunk
#define NR 4                  // node ranges (50KB LDS, 3 blocks/CU)
#define RNG (N_NODES / NR)    // 12500 nodes per range

#define PX_BLOCKS 3125        // prep_x: 50000*16/256
#define PW_BLOCKS 192         // prep_w: 384 half-blocks / 2
#define HIST_BLOCKS (N_REL * EB * NR)  // 512

#define AST 520               // fused-L1 A-tile stride (ushorts): 512 + 8 pad

using short8 = __attribute__((ext_vector_type(8))) short;
using f32x4 = __attribute__((ext_vector_type(4))) float;

static __device__ inline unsigned short f2bf(float f) {
  unsigned u = __float_as_uint(f);
  unsigned r = (u + 0x7FFFu + ((u >> 16) & 1u)) >> 16;
  return (unsigned short)r;
}
static __device__ inline float bf2f(unsigned short b) {
  return __uint_as_float(((unsigned)b) << 16);
}
static __device__ inline void fma_bf2(unsigned w, float ds, float& a0,
                                      float& a1) {
  float lo = __uint_as_float(w << 16);
  float hi = __uint_as_float(w & 0xffff0000u);
  a0 = fmaf(lo, ds, a0);
  a1 = fmaf(hi, ds, a1);
}

// ---------------------------------------------------------------------------
// Fused prep: [0,PX) x->bf16 (+zero chunkSums), [PX,PX+PW) W->bf16^T,
// [PX+PW, ...) per-(rel,chunk,range) histograms into packed 16-bit LDS.
// ---------------------------------------------------------------------------
__global__ __launch_bounds__(256) void k_prep_fused(
    const float* __restrict__ x, const float* __restrict__ W1,
    const float* __restrict__ W2, const int* __restrict__ src,
    const int* __restrict__ dst, unsigned short* __restrict__ xb,
    unsigned short* __restrict__ Wt1, unsigned short* __restrict__ Wt2,
    unsigned short* __restrict__ Hs, unsigned short* __restrict__ Hd,
    int* __restrict__ chunkSums) {
  __shared__ unsigned int ldsS[RNG / 2], ldsD[RNG / 2];
  const int b = blockIdx.x;
  const int tid = threadIdx.x;
  if (b < PX_BLOCKS) {
    if (b == 0 && tid < 64) chunkSums[tid] = 0;
    int i = b * 256 + tid;  // 800000 groups of 8
    const float4* p = (const float4*)x + (size_t)i * 2;
    float4 v0 = p[0], v1 = p[1];
    unsigned short pk[8] = {f2bf(v0.x), f2bf(v0.y), f2bf(v0.z), f2bf(v0.w),
                            f2bf(v1.x), f2bf(v1.y), f2bf(v1.z), f2bf(v1.w)};
    *(uint4*)(xb + (size_t)i * 8) = *(uint4*)pk;
    return;
  }
  if (b < PX_BLOCKS + PW_BLOCKS) {
    int ob = (b - PX_BLOCKS) * 2 + (tid >> 7);  // 0..383
    int kk = tid & 127;
    if (ob < 128) {
      int c = ob;
#pragma unroll
      for (int r = 0; r < 4; ++r)
        Wt1[(size_t)c * 512 + r * 128 + kk] =
            f2bf(W1[(size_t)r * 16384 + kk * 128 + c]);
    } else {
      int c = ob - 128;  // 0..255
      int r = c >> 6, cc = c & 63;
      Wt2[(size_t)c * 128 + kk] = f2bf(W2[(size_t)r * 8192 + kk * 64 + cc]);
    }
    return;
  }
  // histogram part
  const int hb = b - PX_BLOCKS - PW_BLOCKS;
  const int range = hb % NR;
  const int chunk = (hb / NR) % EB;
  const int rel = hb / (NR * EB);
  for (int i = tid; i < RNG / 2; i += 256) {
    ldsS[i] = 0u;
    ldsD[i] = 0u;
  }
  __syncthreads();
  const int n0 = range * RNG;
  const int* sp = src + (size_t)rel * N_EDGES + chunk * ECH;
  const int* dp = dst + (size_t)rel * N_EDGES + chunk * ECH;
  for (int e = tid; e < ECH; e += 256) {
    int s = sp[e] - n0;
    if ((unsigned)s < RNG) atomicAdd(&ldsS[s >> 1], 1u << ((s & 1) * 16));
    int d = dp[e] - n0;
    if ((unsigned)d < RNG) atomicAdd(&ldsD[d >> 1], 1u << ((d & 1) * 16));
  }
  __syncthreads();
  unsigned int* HsO =
      (unsigned int*)(Hs + ((size_t)rel * EB + chunk) * N_NODES + n0);
  unsigned int* HdO =
      (unsigned int*)(Hd + ((size_t)rel * EB + chunk) * N_NODES + n0);
  for (int i = tid; i < RNG / 2; i += 256) {
    HsO[i] = ldsS[i];
    HdO[i] = ldsD[i];
  }
}

// ---------------------------------------------------------------------------
// Per node: dso/dsi, merged count, in-place merged prefix of Hd, relOff,
// and fused per-chunk sums (LDS reduce + one atomic per block).
// ---------------------------------------------------------------------------
__global__ __launch_bounds__(256) void k_reduce_m(
    const unsigned short* __restrict__ Hs, unsigned short* __restrict__ Hd,
    int* __restrict__ cnt_m, float* __restrict__ dso, float* __restrict__ dsi,
    ushort4* __restrict__ relOff, int* __restrict__ chunkSums) {
  int n = blockIdx.x * 256 + threadIdx.x;
  int run = 0;
  if (n < N_NODES) {
#pragma unroll
    for (int r = 0; r < N_REL; ++r) {
      int so = 0;
#pragma unroll
      for (int b = 0; b < EB; ++b)
        so += Hs[((size_t)r * EB + b) * N_NODES + n];
      dso[r * N_NODES + n] = rsqrtf((float)(so < 1 ? 1 : so));
    }
    unsigned short rs[4];
#pragma unroll
    for (int r = 0; r < N_REL; ++r) {
      rs[r] = (unsigned short)run;
#pragma unroll
      for (int b = 0; b < EB; ++b) {
        size_t off = ((size_t)r * EB + b) * N_NODES + n;
        int v = Hd[off];
        Hd[off] = (unsigned short)run;
        run += v;
      }
      int di = run - rs[r];
      dsi[r * N_NODES + n] = rsqrtf((float)(di < 1 ? 1 : di));
    }
    cnt_m[n] = run;
    relOff[n] = make_ushort4(rs[0], rs[1], rs[2], rs[3]);
  }
  __shared__ int red[256];
  red[threadIdx.x] = run;
  __syncthreads();
  for (int off = 128; off > 0; off >>= 1) {
    if (threadIdx.x < off) red[threadIdx.x] += red[threadIdx.x + off];
    __syncthreads();
  }
  if (threadIdx.x == 0) atomicAdd(&chunkSums[blockIdx.x >> 2], red[0]);
}

__global__ __launch_bounds__(64) void k_scan_chunks(int* __restrict__ chunkSums,
                                                    int* __restrict__ row_ptr) {
  if (threadIdx.x == 0) {
    int running = 0;
    for (int c = 0; c < NCHUNK; ++c) {
      int v = chunkSums[c];
      chunkSums[c] = running;
      running += v;
    }
    row_ptr[N_NODES] = N_REL * N_EDGES;
  }
}

__global__ __launch_bounds__(256) void k_scan_within(
    const int* __restrict__ cnt_m, const int* __restrict__ chunkOff,
    int* __restrict__ row_ptr) {
  int c = blockIdx.x;
  int t = threadIdx.x;
  int base = c * CHUNK + t * 4;
  int v[4];
#pragma unroll
  for (int j = 0; j < 4; ++j) {
    int n = base + j;
    v[j] = (n < N_NODES) ? cnt_m[n] : 0;
  }
  int total = v[0] + v[1] + v[2] + v[3];
  __shared__ int lds[256];
  lds[t] = total;
  __syncthreads();
  for (int off = 1; off < 256; off <<= 1) {
    int add = (t >= off) ? lds[t - off] : 0;
    __syncthreads();
    lds[t] += add;
    __syncthreads();
  }
  int thrExcl = lds[t] - total + chunkOff[c];
  int pre = 0;
#pragma unroll
  for (int j = 0; j < 4; ++j) {
    int n = base + j;
    if (n < N_NODES) row_ptr[n] = thrExcl + pre;
    pre += v[j];
  }
}

// ---------------------------------------------------------------------------
// Merged fill: sorted_m[...] = (ushort)src (rel implied by segment position)
// ---------------------------------------------------------------------------
__global__ __launch_bounds__(256) void k_fill2m(
    const int* __restrict__ src, const int* __restrict__ dst,
    const unsigned short* __restrict__ Hd, const int* __restrict__ row_ptr,
    unsigned short* __restrict__ sorted) {
  const int range = blockIdx.x % NR;
  const int chunk = (blockIdx.x / NR) % EB;
  const int rel = blockIdx.x / (NR * EB);
  __shared__ unsigned int cur[RNG];
  const int n0 = range * RNG;
  const int* rp = row_ptr + n0;
  const unsigned short* pref = Hd + ((size_t)rel * EB + chunk) * N_NODES + n0;
  for (int i = threadIdx.x; i < RNG; i += 256)
    cur[i] = (unsigned)(rp[i] + pref[i]);
  __syncthreads();
  const int* sp = src + (size_t)rel * N_EDGES + chunk * ECH;
  const int* dp = dst + (size_t)rel * N_EDGES + chunk * ECH;
  for (int e = threadIdx.x; e < ECH; e += 256) {
    int d = dp[e] - n0;
    if ((unsigned)d < RNG) {
      unsigned pos = atomicAdd(&cur[d], 1u);
      sorted[pos] = (unsigned short)sp[e];
    }
  }
}

// ---------------------------------------------------------------------------
// FUSED layer 1: per block, gather 32 nodes' agg rows [4][128] bf16 into an
// LDS A-tile (stride AST=520 ushorts -> 4-bank row rotation), then the K=512
// MFMA GEMM h1 = relu(A @ Wt1^T + sum_r b1[r]) with B streamed from L2.
// Eliminates the 51.2MB agg write + 51.2MB read of the split version.
// ---------------------------------------------------------------------------
__global__ __launch_bounds__(256, 3) void k_fused_l1(
    const unsigned short* __restrict__ xb, const int* __restrict__ row_ptr,
    const ushort4* __restrict__ relOff, const unsigned short* __restrict__ sortedm,
    const float* __restrict__ dso, const float* __restrict__ dsi,
    const unsigned short* __restrict__ Wt, const float* __restrict__ b1,
    unsigned short* __restrict__ h1) {
  __shared__ unsigned short Atile[32 * AST];  // 33.3KB
  const int wave = threadIdx.x >> 6, lane = threadIdx.x & 63;
  const int g = lane & 31;
  const int nodeBase = blockIdx.x * 32;

  // ---- gather phase: 4 passes, 2 nodes per wave per pass ----
  for (int p = 0; p < 4; ++p) {
    const int local = p * 8 + wave * 2 + (lane >> 5);
    const int node = nodeBase + local;
    if (node < N_NODES) {
      const int rp = row_ptr[node], rp1 = row_ptr[node + 1];
      const ushort4 ro = relOff[node];
      const int beg[4] = {rp + ro.x, rp + ro.y, rp + ro.z, rp + ro.w};
      const int end4[4] = {rp + ro.y, rp + ro.z, rp + ro.w, rp1};
#pragma unroll
      for (int r = 0; r < 4; ++r) {
        const float* dsoR = dso + (size_t)r * N_NODES;
        float a0[4] = {0, 0, 0, 0}, a1[4] = {0, 0, 0, 0};
        float a2[4] = {0, 0, 0, 0}, a3[4] = {0, 0, 0, 0};
        for (int base = beg[r]; base < end4[r]; base += 32) {
          int n = end4[r] - base;
          if (n > 32) n = 32;
          int my = (g < n) ? (int)sortedm[base + g] : 0;
          int j = 0;
          for (; j + 3 < n; j += 4) {
#pragma unroll
            for (int k = 0; k < 4; ++k) {
              int s = __shfl(my, j + k, 32);
              float ds = dsoR[s];
              uint2 w = *(const uint2*)(xb + (size_t)s * 128 + g * 4);
              fma_bf2(w.x, ds, a0[k], a1[k]);
              fma_bf2(w.y, ds, a2[k], a3[k]);
            }
          }
          for (; j < n; ++j) {
            int s = __shfl(my, j, 32);
            float ds = dsoR[s];
            uint2 w = *(const uint2*)(xb + (size_t)s * 128 + g * 4);
            fma_bf2(w.x, ds, a0[0], a1[0]);
            fma_bf2(w.y, ds, a2[0], a3[0]);
          }
        }
        float di = dsi[(size_t)r * N_NODES + node];
        float t0 = ((a0[0] + a0[1]) + (a0[2] + a0[3])) * di;
        float t1 = ((a1[0] + a1[1]) + (a1[2] + a1[3])) * di;
        float t2 = ((a2[0] + a2[1]) + (a2[2] + a2[3])) * di;
        float t3 = ((a3[0] + a3[1]) + (a3[2] + a3[3])) * di;
        uint2 pk;
        pk.x = (unsigned)f2bf(t0) | ((unsigned)f2bf(t1) << 16);
        pk.y = (unsigned)f2bf(t2) | ((unsigned)f2bf(t3) << 16);
        *((uint2*)(Atile + local * AST + r * 128 + g * 4)) = pk;
      }
    } else {
      uint2 z = make_uint2(0u, 0u);
#pragma unroll
      for (int r = 0; r < 4; ++r)
        *((uint2*)(Atile + local * AST + r * 128 + g * 4)) = z;
    }
  }
  __syncthreads();

  // ---- GEMM phase: C tile [32 rows][128 cols]; wave computes [32][32] ----
  const int lrow = lane & 15, quarter = lane >> 4;
  f32x4 acc[2][2];
#pragma unroll
  for (int i = 0; i < 2; ++i)
#pragma unroll
    for (int j = 0; j < 2; ++j) acc[i][j] = (f32x4){0.f, 0.f, 0.f, 0.f};
  const unsigned short* WtW = Wt + (size_t)(wave * 32) * 512;
#pragma unroll 4
  for (int kk = 0; kk < 16; ++kk) {
    int kg = kk * 4 + quarter;
    short8 a0 = *(const short8*)(Atile + (0 * 16 + lrow) * AST + kg * 8);
    short8 a1 = *(const short8*)(Atile + (1 * 16 + lrow) * AST + kg * 8);
    short8 b0 = *(const short8*)(WtW + (size_t)(0 * 16 + lrow) * 512 + kg * 8);
    short8 b1v = *(const short8*)(WtW + (size_t)(1 * 16 + lrow) * 512 + kg * 8);
    acc[0][0] = __builtin_amdgcn_mfma_f32_16x16x32_bf16(a0, b0, acc[0][0], 0, 0, 0);
    acc[0][1] = __builtin_amdgcn_mfma_f32_16x16x32_bf16(a0, b1v, acc[0][1], 0, 0, 0);
    acc[1][0] = __builtin_amdgcn_mfma_f32_16x16x32_bf16(a1, b0, acc[1][0], 0, 0, 0);
    acc[1][1] = __builtin_amdgcn_mfma_f32_16x16x32_bf16(a1, b1v, acc[1][1], 0, 0, 0);
  }
#pragma unroll
  for (int j = 0; j < 2; ++j) {
    int c = wave * 32 + j * 16 + lrow;
    float bs = b1[c] + b1[128 + c] + b1[256 + c] + b1[384 + c];
#pragma unroll
    for (int i = 0; i < 2; ++i) {
#pragma unroll
      for (int rr = 0; rr < 4; ++rr) {
        int grow = nodeBase + i * 16 + quarter * 4 + rr;
        if (grow < N_NODES)
          h1[(size_t)grow * 128 + c] = f2bf(fmaxf(acc[i][j][rr] + bs, 0.f));
      }
    }
  }
}

// ---------------------------------------------------------------------------
// Layer-2 bf16 MFMA GEMM: Y2 = (h1 @ Wt2^T)*dso, bf16 (unchanged)
// ---------------------------------------------------------------------------
template <int REL_COLS>
__global__ __launch_bounds__(256, 2) void k_gemm_mfma(
    const unsigned short* __restrict__ A, const unsigned short* __restrict__ Wt,
    const float* __restrict__ dsoBase, unsigned short* __restrict__ C,
    int cstride, int M) {
  __shared__ unsigned short Alds[64 * 128];
  __shared__ unsigned short Wlds[256 * 128];
  const int tid = threadIdx.x;
  const int wid = tid >> 6, lane = tid & 63;
  const int rowBase = blockIdx.x * 64;

#pragma unroll
  for (int i = 0; i < 4; ++i) {
    int cid = tid + i * 256;
    int row = cid >> 4, kg = cid & 15;
    int grow = rowBase + row;
    uint4 v = make_uint4(0, 0, 0, 0);
    if (grow < M) v = *(const uint4*)(A + (size_t)grow * 128 + kg * 8);
    *(uint4*)(Alds + row * 128 + ((kg ^ (row & 7)) * 8)) = v;
  }
#pragma unroll
  for (int i = 0; i < 16; ++i) {
    int cid = tid + i * 256;
    int row = cid >> 4, kg = cid & 15;
    uint4 v = *(const uint4*)(Wt + (size_t)row * 128 + kg * 8);
    *(uint4*)(Wlds + row * 128 + ((kg ^ (row & 7)) * 8)) = v;
  }
  __syncthreads();

  f32x4 acc[4][4];
#pragma unroll
  for (int i = 0; i < 4; ++i)
#pragma unroll
    for (int j = 0; j < 4; ++j) acc[i][j] = (f32x4){0.f, 0.f, 0.f, 0.f};

  const int lrow = lane & 15;
  const int khalf = lane >> 4;
#pragma unroll
  for (int k0 = 0; k0 < 4; ++k0) {
    int kg = k0 * 4 + khalf;
    short8 a[4], b[4];
#pragma unroll
    for (int i = 0; i < 4; ++i) {
      int row = i * 16 + lrow;
      a[i] = *(const short8*)(Alds + row * 128 + ((kg ^ (row & 7)) * 8));
    }
#pragma unroll
    for (int j = 0; j < 4; ++j) {
      int wrow = wid * 64 + j * 16 + lrow;
      b[j] = *(const short8*)(Wlds + wrow * 128 + ((kg ^ (wrow & 7)) * 8));
    }
#pragma unroll
    for (int i = 0; i < 4; ++i)
#pragma unroll
      for (int j = 0; j < 4; ++j)
        acc[i][j] = __builtin_amdgcn_mfma_f32_16x16x32_bf16(a[i], b[j],
                                                            acc[i][j], 0, 0, 0);
  }

#pragma unroll
  for (int i = 0; i < 4; ++i) {
#pragma unroll
    for (int j = 0; j < 4; ++j) {
      int col = wid * 64 + j * 16 + (lane & 15);
      const float* dsoCol = dsoBase + (size_t)(col / REL_COLS) * N_NODES;
#pragma unroll
      for (int r = 0; r < 4; ++r) {
        int grow = rowBase + i * 16 + (lane >> 4) * 4 + r;
        if (grow < M)
          C[(size_t)grow * cstride + col] = f2bf(acc[i][j][r] * dsoCol[grow]);
      }
    }
  }
}

// ---------------------------------------------------------------------------
// Layer-2 gather (per-rel segments, 16 lanes/node): Y2 [node][4][64] bf16 ->
// out fp32 (+bias).
// ---------------------------------------------------------------------------
__global__ __launch_bounds__(256) void k_gather2m(
    const unsigned short* __restrict__ Y, const int* __restrict__ row_ptr,
    const ushort4* __restrict__ relOff, const unsigned short* __restrict__ sortedm,
    const float* __restrict__ dsi, const float* __restrict__ b2,
    float* __restrict__ out) {
  const int wave = threadIdx.x >> 6, lane = threadIdx.x & 63;
  const int g = lane & 15;
  const int node = blockIdx.x * 16 + wave * 4 + (lane >> 4);  // 50000=16*3125
  const int rp = row_ptr[node], rp1 = row_ptr[node + 1];
  const ushort4 ro = relOff[node];
  const int beg[4] = {rp + ro.x, rp + ro.y, rp + ro.z, rp + ro.w};
  const int end4[4] = {rp + ro.y, rp + ro.z, rp + ro.w, rp1};
  float t0 = 0.f, t1 = 0.f, t2 = 0.f, t3 = 0.f;
#pragma unroll
  for (int r = 0; r < 4; ++r) {
    float a0[4] = {0, 0, 0, 0}, a1[4] = {0, 0, 0, 0};
    float a2[4] = {0, 0, 0, 0}, a3[4] = {0, 0, 0, 0};
    for (int base = beg[r]; base < end4[r]; base += 16) {
      int n = end4[r] - base;
      if (n > 16) n = 16;
      int my = (g < n) ? (int)sortedm[base + g] : 0;
      int j = 0;
      for (; j + 3 < n; j += 4) {
#pragma unroll
        for (int k = 0; k < 4; ++k) {
          int s = __shfl(my, j + k, 16);
          uint2 w = *(const uint2*)(Y + ((size_t)s * 4 + r) * 64 + g * 4);
          fma_bf2(w.x, 1.f, a0[k], a1[k]);
          fma_bf2(w.y, 1.f, a2[k], a3[k]);
        }
      }
      for (; j < n; ++j) {
        int s = __shfl(my, j, 16);
        uint2 w = *(const uint2*)(Y + ((size_t)s * 4 + r) * 64 + g * 4);
        fma_bf2(w.x, 1.f, a0[0], a1[0]);
        fma_bf2(w.y, 1.f, a2[0], a3[0]);
      }
    }
    float di = dsi[(size_t)r * N_NODES + node];
    t0 = fmaf((a0[0] + a0[1]) + (a0[2] + a0[3]), di, t0);
    t1 = fmaf((a1[0] + a1[1]) + (a1[2] + a1[3]), di, t1);
    t2 = fmaf((a2[0] + a2[1]) + (a2[2] + a2[3]), di, t2);
    t3 = fmaf((a3[0] + a3[1]) + (a3[2] + a3[3]), di, t3);
  }
#pragma unroll
  for (int r = 0; r < 4; ++r) {
    float4 bb = *(const float4*)(b2 + r * 64 + g * 4);
    t0 += bb.x;
    t1 += bb.y;
    t2 += bb.z;
    t3 += bb.w;
  }
  *(float4*)(out + (size_t)node * 64 + g * 4) = make_float4(t0, t1, t2, t3);
}

extern "C" void kernel_launch(void* const* d_in, const int* in_sizes, int n_in,
                              void* d_out, int out_size, void* d_ws,
                              size_t ws_size, hipStream_t stream) {
  const float* x  = (const float*)d_in[0];
  const int* src  = (const int*)d_in[1];
  const int* dst  = (const int*)d_in[2];
  const float* W1 = (const float*)d_in[3];
  const float* b1 = (const float*)d_in[4];
  const float* W2 = (const float*)d_in[5];
  const float* b2 = (const float*)d_in[6];
  float* out = (float*)d_out;

  // Workspace layout:
  //   [0, 12.8MB)     Hs -- aliased by h1 bf16 (Hs dead after reduce_m)
  //   [12.8, 25.6MB)  Hd (alive until fill2m)
  //   [25.6, 38.4MB)  xb bf16 [50000][128]
  //   [38.4, 64.0MB)  Y2 bf16 [50000][4][64]
  //   tail: Wt1 | Wt2 | dso | dsi | relOff | cnt_m | row_ptr | chunkSums | sorted(ushort)
  char* wsb = (char*)d_ws;
  unsigned short* Hs = (unsigned short*)wsb;                 // 12.8MB
  unsigned short* h1 = (unsigned short*)wsb;                 // alias
  unsigned short* Hd = Hs + (size_t)N_REL * EB * N_NODES;    // 12.8MB
  unsigned short* xb = Hd + (size_t)N_REL * EB * N_NODES;    // 12.8MB
  unsigned short* Y2 = xb + (size_t)N_NODES * 128;           // 25.6MB
  char* tail = (char*)(Y2 + (size_t)N_NODES * 256);
  unsigned short* Wt1 = (unsigned short*)tail;               // 128KB
  unsigned short* Wt2 = Wt1 + 128 * 512;                     // 64KB
  float* dso = (float*)(Wt2 + 256 * 128);                    // 800KB
  float* dsi = dso + N_REL * N_NODES;                        // 800KB
  ushort4* relOff = (ushort4*)(dsi + N_REL * N_NODES);       // 400KB
  int* cnt_m = (int*)(relOff + N_NODES);                     // 200KB
  int* row_ptr = cnt_m + N_NODES;                            // 200KB
  int* chunkSums = row_ptr + (N_NODES + 1);                  // ~256B
  unsigned short* sorted = (unsigned short*)(chunkSums + 64);  // 3.2MB

  k_prep_fused<<<PX_BLOCKS + PW_BLOCKS + HIST_BLOCKS, 256, 0, stream>>>(
      x, W1, W2, src, dst, xb, Wt1, Wt2, Hs, Hd, chunkSums);
  k_reduce_m<<<(N_NODES + 255) / 256, 256, 0, stream>>>(Hs, Hd, cnt_m, dso,
                                                        dsi, relOff, chunkSums);
  k_scan_chunks<<<1, 64, 0, stream>>>(chunkSums, row_ptr);
  k_scan_within<<<NCHUNK, 256, 0, stream>>>(cnt_m, chunkSums, row_ptr);
  k_fill2m<<<N_REL * EB * NR, 256, 0, stream>>>(src, dst, Hd, row_ptr, sorted);

  // Layer 1: fused gather + K=512 MFMA GEMM (+bias+ReLU) -> h1
  k_fused_l1<<<(N_NODES + 31) / 32, 256, 0, stream>>>(
      xb, row_ptr, relOff, sorted, dso, dsi, Wt1, b1, h1);
  // Layer 2: transform-first GEMM into Y2 [node][4][64], then gather
  k_gemm_mfma<64><<<(N_NODES + 63) / 64, 256, 0, stream>>>(h1, Wt2, dso, Y2,
                                                           256, N_NODES);
  k_gather2m<<<N_NODES / 16, 256, 0, stream>>>(Y2, row_ptr, relOff, sorted,
                                               dsi, b2, out);
}

// Round 15
// 265.347 us; speedup vs baseline: 1.1085x; 1.1085x over previous
//
#include <hip/hip_runtime.h>
#include <hip/hip_bf16.h>

#define N_NODES 50000
#define N_REL 4
#define N_EDGES 400000
#define CHUNK 1024
#define NCHUNK ((N_NODES + CHUNK - 1) / CHUNK)  // 49

#define EB 32                 // edge chunks per relation
#define ECH (N_EDGES / EB)    // 12500 edges per chunk
#define NR 4                  // node ranges (50KB LDS in hist/fill, 3 blk/CU)
#define RNG (N_NODES / NR)    // 12500 nodes per range

#define PX_BLOCKS 3125        // prep_x: 50000*16/256
#define PW_BLOCKS 192         // prep_w: 384 half-blocks / 2
#define HIST_BLOCKS (N_REL * EB * NR)  // 512

using short8 = __attribute__((ext_vector_type(8))) short;
using f32x4 = __attribute__((ext_vector_type(4))) float;

static __device__ inline unsigned short f2bf(float f) {
  unsigned u = __float_as_uint(f);
  unsigned r = (u + 0x7FFFu + ((u >> 16) & 1u)) >> 16;
  return (unsigned short)r;
}
static __device__ inline float bf2f(unsigned short b) {
  return __uint_as_float(((unsigned)b) << 16);
}
static __device__ inline void fma_bf2(unsigned w, float ds, float& a0,
                                      float& a1) {
  float lo = __uint_as_float(w << 16);
  float hi = __uint_as_float(w & 0xffff0000u);
  a0 = fmaf(lo, ds, a0);
  a1 = fmaf(hi, ds, a1);
}

// ---------------------------------------------------------------------------
// Fused prep: [0,PX) x->bf16 (+zero chunkSums), [PX,PX+PW) W->bf16^T,
// [PX+PW, ...) per-(rel,chunk,range) histograms into packed 16-bit LDS.
// ---------------------------------------------------------------------------
__global__ __launch_bounds__(256) void k_prep_fused(
    const float* __restrict__ x, const float* __restrict__ W1,
    const float* __restrict__ W2, const int* __restrict__ src,
    const int* __restrict__ dst, unsigned short* __restrict__ xb,
    unsigned short* __restrict__ Wt1, unsigned short* __restrict__ Wt2,
    unsigned short* __restrict__ Hs, unsigned short* __restrict__ Hd,
    int* __restrict__ chunkSums) {
  __shared__ unsigned int ldsS[RNG / 2], ldsD[RNG / 2];
  const int b = blockIdx.x;
  const int tid = threadIdx.x;
  if (b < PX_BLOCKS) {
    if (b == 0 && tid < 64) chunkSums[tid] = 0;
    int i = b * 256 + tid;  // 800000 groups of 8
    const float4* p = (const float4*)x + (size_t)i * 2;
    float4 v0 = p[0], v1 = p[1];
    unsigned short pk[8] = {f2bf(v0.x), f2bf(v0.y), f2bf(v0.z), f2bf(v0.w),
                            f2bf(v1.x), f2bf(v1.y), f2bf(v1.z), f2bf(v1.w)};
    *(uint4*)(xb + (size_t)i * 8) = *(uint4*)pk;
    return;
  }
  if (b < PX_BLOCKS + PW_BLOCKS) {
    int ob = (b - PX_BLOCKS) * 2 + (tid >> 7);  // 0..383
    int kk = tid & 127;
    if (ob < 128) {
      int c = ob;
#pragma unroll
      for (int r = 0; r < 4; ++r)
        Wt1[(size_t)c * 512 + r * 128 + kk] =
            f2bf(W1[(size_t)r * 16384 + kk * 128 + c]);
    } else {
      int c = ob - 128;  // 0..255
      int r = c >> 6, cc = c & 63;
      Wt2[(size_t)c * 128 + kk] = f2bf(W2[(size_t)r * 8192 + kk * 64 + cc]);
    }
    return;
  }
  // histogram part
  const int hb = b - PX_BLOCKS - PW_BLOCKS;
  const int range = hb % NR;
  const int chunk = (hb / NR) % EB;
  const int rel = hb / (NR * EB);
  for (int i = tid; i < RNG / 2; i += 256) {
    ldsS[i] = 0u;
    ldsD[i] = 0u;
  }
  __syncthreads();
  const int n0 = range * RNG;
  const int* sp = src + (size_t)rel * N_EDGES + chunk * ECH;
  const int* dp = dst + (size_t)rel * N_EDGES + chunk * ECH;
  for (int e = tid; e < ECH; e += 256) {
    int s = sp[e] - n0;
    if ((unsigned)s < RNG) atomicAdd(&ldsS[s >> 1], 1u << ((s & 1) * 16));
    int d = dp[e] - n0;
    if ((unsigned)d < RNG) atomicAdd(&ldsD[d >> 1], 1u << ((d & 1) * 16));
  }
  __syncthreads();
  unsigned int* HsO =
      (unsigned int*)(Hs + ((size_t)rel * EB + chunk) * N_NODES + n0);
  unsigned int* HdO =
      (unsigned int*)(Hd + ((size_t)rel * EB + chunk) * N_NODES + n0);
  for (int i = tid; i < RNG / 2; i += 256) {
    HsO[i] = ldsS[i];
    HdO[i] = ldsD[i];
  }
}

// ---------------------------------------------------------------------------
// Per node: dso/dsi, merged count, in-place merged prefix of Hd, relOff,
// and fused per-chunk sums (LDS reduce + one atomic per block).
// ---------------------------------------------------------------------------
__global__ __launch_bounds__(256) void k_reduce_m(
    const unsigned short* __restrict__ Hs, unsigned short* __restrict__ Hd,
    int* __restrict__ cnt_m, float* __restrict__ dso, float* __restrict__ dsi,
    ushort4* __restrict__ relOff, int* __restrict__ chunkSums) {
  int n = blockIdx.x * 256 + threadIdx.x;
  int run = 0;
  if (n < N_NODES) {
#pragma unroll
    for (int r = 0; r < N_REL; ++r) {
      int so = 0;
#pragma unroll
      for (int b = 0; b < EB; ++b)
        so += Hs[((size_t)r * EB + b) * N_NODES + n];
      dso[r * N_NODES + n] = rsqrtf((float)(so < 1 ? 1 : so));
    }
    unsigned short rs[4];
#pragma unroll
    for (int r = 0; r < N_REL; ++r) {
      rs[r] = (unsigned short)run;
#pragma unroll
      for (int b = 0; b < EB; ++b) {
        size_t off = ((size_t)r * EB + b) * N_NODES + n;
        int v = Hd[off];
        Hd[off] = (unsigned short)run;
        run += v;
      }
      int di = run - rs[r];
      dsi[r * N_NODES + n] = rsqrtf((float)(di < 1 ? 1 : di));
    }
    cnt_m[n] = run;
    relOff[n] = make_ushort4(rs[0], rs[1], rs[2], rs[3]);
  }
  __shared__ int red[256];
  red[threadIdx.x] = run;
  __syncthreads();
  for (int off = 128; off > 0; off >>= 1) {
    if (threadIdx.x < off) red[threadIdx.x] += red[threadIdx.x + off];
    __syncthreads();
  }
  if (threadIdx.x == 0) atomicAdd(&chunkSums[blockIdx.x >> 2], red[0]);
}

__global__ __launch_bounds__(64) void k_scan_chunks(int* __restrict__ chunkSums,
                                                    int* __restrict__ row_ptr) {
  if (threadIdx.x == 0) {
    int running = 0;
    for (int c = 0; c < NCHUNK; ++c) {
      int v = chunkSums[c];
      chunkSums[c] = running;
      running += v;
    }
    row_ptr[N_NODES] = N_REL * N_EDGES;
  }
}

__global__ __launch_bounds__(256) void k_scan_within(
    const int* __restrict__ cnt_m, const int* __restrict__ chunkOff,
    int* __restrict__ row_ptr) {
  int c = blockIdx.x;
  int t = threadIdx.x;
  int base = c * CHUNK + t * 4;
  int v[4];
#pragma unroll
  for (int j = 0; j < 4; ++j) {
    int n = base + j;
    v[j] = (n < N_NODES) ? cnt_m[n] : 0;
  }
  int total = v[0] + v[1] + v[2] + v[3];
  __shared__ int lds[256];
  lds[t] = total;
  __syncthreads();
  for (int off = 1; off < 256; off <<= 1) {
    int add = (t >= off) ? lds[t - off] : 0;
    __syncthreads();
    lds[t] += add;
    __syncthreads();
  }
  int thrExcl = lds[t] - total + chunkOff[c];
  int pre = 0;
#pragma unroll
  for (int j = 0; j < 4; ++j) {
    int n = base + j;
    if (n < N_NODES) row_ptr[n] = thrExcl + pre;
    pre += v[j];
  }
}

// ---------------------------------------------------------------------------
// Merged fill: sorted_m[...] = (ushort)src (rel implied by segment position)
// ---------------------------------------------------------------------------
__global__ __launch_bounds__(256) void k_fill2m(
    const int* __restrict__ src, const int* __restrict__ dst,
    const unsigned short* __restrict__ Hd, const int* __restrict__ row_ptr,
    unsigned short* __restrict__ sorted) {
  const int range = blockIdx.x % NR;
  const int chunk = (blockIdx.x / NR) % EB;
  const int rel = blockIdx.x / (NR * EB);
  __shared__ unsigned int cur[RNG];
  const int n0 = range * RNG;
  const int* rp = row_ptr + n0;
  const unsigned short* pref = Hd + ((size_t)rel * EB + chunk) * N_NODES + n0;
  for (int i = threadIdx.x; i < RNG; i += 256)
    cur[i] = (unsigned)(rp[i] + pref[i]);
  __syncthreads();
  const int* sp = src + (size_t)rel * N_EDGES + chunk * ECH;
  const int* dp = dst + (size_t)rel * N_EDGES + chunk * ECH;
  for (int e = threadIdx.x; e < ECH; e += 256) {
    int d = dp[e] - n0;
    if ((unsigned)d < RNG) {
      unsigned pos = atomicAdd(&cur[d], 1u);
      sorted[pos] = (unsigned short)sp[e];
    }
  }
}

// ---------------------------------------------------------------------------
// Aggregate-first layer-1 gather (proven round-13 form): 32 lanes/node,
// full 256-B row consumed per edge (line-optimal), per-rel segments.
//   agg[node][r][:] = dsi_r[node] * sum_e dso_r[s]*x[s]
// ---------------------------------------------------------------------------
__global__ __launch_bounds__(256) void k_gather1a(
    const unsigned short* __restrict__ xb, const int* __restrict__ row_ptr,
    const ushort4* __restrict__ relOff, const unsigned short* __restrict__ sortedm,
    const float* __restrict__ dso, const float* __restrict__ dsi,
    unsigned int* __restrict__ agg) {
  const int wave = threadIdx.x >> 6, lane = threadIdx.x & 63;
  const int g = lane & 31;
  const int node = blockIdx.x * 8 + wave * 2 + (lane >> 5);  // 50000 = 8*6250
  const int rp = row_ptr[node], rp1 = row_ptr[node + 1];
  const ushort4 ro = relOff[node];
  const int beg[4] = {rp + ro.x, rp + ro.y, rp + ro.z, rp + ro.w};
  const int end4[4] = {rp + ro.y, rp + ro.z, rp + ro.w, rp1};
#pragma unroll
  for (int r = 0; r < 4; ++r) {
    const float* dsoR = dso + (size_t)r * N_NODES;
    float a0[4] = {0, 0, 0, 0}, a1[4] = {0, 0, 0, 0};
    float a2[4] = {0, 0, 0, 0}, a3[4] = {0, 0, 0, 0};
    for (int base = beg[r]; base < end4[r]; base += 32) {
      int n = end4[r] - base;
      if (n > 32) n = 32;
      int my = (g < n) ? (int)sortedm[base + g] : 0;
      int j = 0;
      for (; j + 3 < n; j += 4) {
#pragma unroll
        for (int k = 0; k < 4; ++k) {
          int s = __shfl(my, j + k, 32);
          float ds = dsoR[s];
          uint2 w = *(const uint2*)(xb + (size_t)s * 128 + g * 4);
          fma_bf2(w.x, ds, a0[k], a1[k]);
          fma_bf2(w.y, ds, a2[k], a3[k]);
        }
      }
      for (; j < n; ++j) {
        int s = __shfl(my, j, 32);
        float ds = dsoR[s];
        uint2 w = *(const uint2*)(xb + (size_t)s * 128 + g * 4);
        fma_bf2(w.x, ds, a0[0], a1[0]);
        fma_bf2(w.y, ds, a2[0], a3[0]);
      }
    }
    float di = dsi[(size_t)r * N_NODES + node];
    float t0 = ((a0[0] + a0[1]) + (a0[2] + a0[3])) * di;
    float t1 = ((a1[0] + a1[1]) + (a1[2] + a1[3])) * di;
    float t2 = ((a2[0] + a2[1]) + (a2[2] + a2[3])) * di;
    float t3 = ((a3[0] + a3[1]) + (a3[2] + a3[3])) * di;
    uint2 pk;
    pk.x = (unsigned)f2bf(t0) | ((unsigned)f2bf(t1) << 16);
    pk.y = (unsigned)f2bf(t2) | ((unsigned)f2bf(t3) << 16);
    *((uint2*)agg + ((size_t)node * 4 + r) * 32 + g) = pk;
  }
}

// ---------------------------------------------------------------------------
// h1 = relu(agg[50000][512] @ Wt1cat^T + sum_r b1[r]) -> bf16
// ---------------------------------------------------------------------------
__global__ __launch_bounds__(256, 2) void k_gemm_h1(
    const unsigned short* __restrict__ agg, const unsigned short* __restrict__ Wt,
    const float* __restrict__ b1, unsigned short* __restrict__ h1, int M) {
  __shared__ unsigned short Alds[64 * 128];
  __shared__ unsigned short Wlds[128 * 128];
  const int tid = threadIdx.x;
  const int wid = tid >> 6, lane = tid & 63;
  const int rowBase = blockIdx.x * 64;
  const int lrow = lane & 15;
  const int quarter = lane >> 4;

  f32x4 acc[4][2];
#pragma unroll
  for (int i = 0; i < 4; ++i)
#pragma unroll
    for (int j = 0; j < 2; ++j) acc[i][j] = (f32x4){0.f, 0.f, 0.f, 0.f};

  for (int k0 = 0; k0 < 4; ++k0) {
    __syncthreads();
#pragma unroll
    for (int it = 0; it < 4; ++it) {
      int cid = tid + it * 256;
      int row = cid >> 4, kg = cid & 15;
      int grow = rowBase + row;
      uint4 v = make_uint4(0, 0, 0, 0);
      if (grow < M)
        v = *(const uint4*)(agg + (size_t)grow * 512 + k0 * 128 + kg * 8);
      *(uint4*)(Alds + row * 128 + ((kg ^ (row & 7)) * 8)) = v;
    }
#pragma unroll
    for (int it = 0; it < 8; ++it) {
      int cid = tid + it * 256;
      int c = cid >> 4, kg = cid & 15;
      uint4 v = *(const uint4*)(Wt + (size_t)c * 512 + k0 * 128 + kg * 8);
      *(uint4*)(Wlds + c * 128 + ((kg ^ (c & 7)) * 8)) = v;
    }
    __syncthreads();
#pragma unroll
    for (int kk = 0; kk < 4; ++kk) {
      int kg = kk * 4 + quarter;
      short8 a[4], b[2];
#pragma unroll
      for (int i = 0; i < 4; ++i) {
        int row = i * 16 + lrow;
        a[i] = *(const short8*)(Alds + row * 128 + ((kg ^ (row & 7)) * 8));
      }
#pragma unroll
      for (int j = 0; j < 2; ++j) {
        int c = wid * 32 + j * 16 + lrow;
        b[j] = *(const short8*)(Wlds + c * 128 + ((kg ^ (c & 7)) * 8));
      }
#pragma unroll
      for (int i = 0; i < 4; ++i)
#pragma unroll
        for (int j = 0; j < 2; ++j)
          acc[i][j] = __builtin_amdgcn_mfma_f32_16x16x32_bf16(a[i], b[j],
                                                              acc[i][j], 0, 0, 0);
    }
  }

#pragma unroll
  for (int j = 0; j < 2; ++j) {
    int c = wid * 32 + j * 16 + lrow;
    float bs = b1[c] + b1[128 + c] + b1[256 + c] + b1[384 + c];
#pragma unroll
    for (int i = 0; i < 4; ++i) {
#pragma unroll
      for (int r = 0; r < 4; ++r) {
        int grow = rowBase + i * 16 + quarter * 4 + r;
        if (grow < M)
          h1[(size_t)grow * 128 + c] = f2bf(fmaxf(acc[i][j][r] + bs, 0.f));
      }
    }
  }
}

// ---------------------------------------------------------------------------
// Layer-2 bf16 MFMA GEMM: Y2 = (h1 @ Wt2^T)*dso, bf16
// ---------------------------------------------------------------------------
template <int REL_COLS>
__global__ __launch_bounds__(256, 2) void k_gemm_mfma(
    const unsigned short* __restrict__ A, const unsigned short* __restrict__ Wt,
    const float* __restrict__ dsoBase, unsigned short* __restrict__ C,
    int cstride, int M) {
  __shared__ unsigned short Alds[64 * 128];
  __shared__ unsigned short Wlds[256 * 128];
  const int tid = threadIdx.x;
  const int wid = tid >> 6, lane = tid & 63;
  const int rowBase = blockIdx.x * 64;

#pragma unroll
  for (int i = 0; i < 4; ++i) {
    int cid = tid + i * 256;
    int row = cid >> 4, kg = cid & 15;
    int grow = rowBase + row;
    uint4 v = make_uint4(0, 0, 0, 0);
    if (grow < M) v = *(const uint4*)(A + (size_t)grow * 128 + kg * 8);
    *(uint4*)(Alds + row * 128 + ((kg ^ (row & 7)) * 8)) = v;
  }
#pragma unroll
  for (int i = 0; i < 16; ++i) {
    int cid = tid + i * 256;
    int row = cid >> 4, kg = cid & 15;
    uint4 v = *(const uint4*)(Wt + (size_t)row * 128 + kg * 8);
    *(uint4*)(Wlds + row * 128 + ((kg ^ (row & 7)) * 8)) = v;
  }
  __syncthreads();

  f32x4 acc[4][4];
#pragma unroll
  for (int i = 0; i < 4; ++i)
#pragma unroll
    for (int j = 0; j < 4; ++j) acc[i][j] = (f32x4){0.f, 0.f, 0.f, 0.f};

  const int lrow = lane & 15;
  const int khalf = lane >> 4;
#pragma unroll
  for (int k0 = 0; k0 < 4; ++k0) {
    int kg = k0 * 4 + khalf;
    short8 a[4], b[4];
#pragma unroll
    for (int i = 0; i < 4; ++i) {
      int row = i * 16 + lrow;
      a[i] = *(const short8*)(Alds + row * 128 + ((kg ^ (row & 7)) * 8));
    }
#pragma unroll
    for (int j = 0; j < 4; ++j) {
      int wrow = wid * 64 + j * 16 + lrow;
      b[j] = *(const short8*)(Wlds + wrow * 128 + ((kg ^ (wrow & 7)) * 8));
    }
#pragma unroll
    for (int i = 0; i < 4; ++i)
#pragma unroll
      for (int j = 0; j < 4; ++j)
        acc[i][j] = __builtin_amdgcn_mfma_f32_16x16x32_bf16(a[i], b[j],
                                                            acc[i][j], 0, 0, 0);
  }

#pragma unroll
  for (int i = 0; i < 4; ++i) {
#pragma unroll
    for (int j = 0; j < 4; ++j) {
      int col = wid * 64 + j * 16 + (lane & 15);
      const float* dsoCol = dsoBase + (size_t)(col / REL_COLS) * N_NODES;
#pragma unroll
      for (int r = 0; r < 4; ++r) {
        int grow = rowBase + i * 16 + (lane >> 4) * 4 + r;
        if (grow < M)
          C[(size_t)grow * cstride + col] = f2bf(acc[i][j][r] * dsoCol[grow]);
      }
    }
  }
}

// ---------------------------------------------------------------------------
// Layer-2 gather (per-rel segments, 16 lanes/node): Y2 [node][4][64] bf16 ->
// out fp32 (+bias).
// ---------------------------------------------------------------------------
__global__ __launch_bounds__(256) void k_gather2m(
    const unsigned short* __restrict__ Y, const int* __restrict__ row_ptr,
    const ushort4* __restrict__ relOff, const unsigned short* __restrict__ sortedm,
    const float* __restrict__ dsi, const float* __restrict__ b2,
    float* __restrict__ out) {
  const int wave = threadIdx.x >> 6, lane = threadIdx.x & 63;
  const int g = lane & 15;
  const int node = blockIdx.x * 16 + wave * 4 + (lane >> 4);  // 50000=16*3125
  const int rp = row_ptr[node], rp1 = row_ptr[node + 1];
  const ushort4 ro = relOff[node];
  const int beg[4] = {rp + ro.x, rp + ro.y, rp + ro.z, rp + ro.w};
  const int end4[4] = {rp + ro.y, rp + ro.z, rp + ro.w, rp1};
  float t0 = 0.f, t1 = 0.f, t2 = 0.f, t3 = 0.f;
#pragma unroll
  for (int r = 0; r < 4; ++r) {
    float a0[4] = {0, 0, 0, 0}, a1[4] = {0, 0, 0, 0};
    float a2[4] = {0, 0, 0, 0}, a3[4] = {0, 0, 0, 0};
    for (int base = beg[r]; base < end4[r]; base += 16) {
      int n = end4[r] - base;
      if (n > 16) n = 16;
      int my = (g < n) ? (int)sortedm[base + g] : 0;
      int j = 0;
      for (; j + 3 < n; j += 4) {
#pragma unroll
        for (int k = 0; k < 4; ++k) {
          int s = __shfl(my, j + k, 16);
          uint2 w = *(const uint2*)(Y + ((size_t)s * 4 + r) * 64 + g * 4);
          fma_bf2(w.x, 1.f, a0[k], a1[k]);
          fma_bf2(w.y, 1.f, a2[k], a3[k]);
        }
      }
      for (; j < n; ++j) {
        int s = __shfl(my, j, 16);
        uint2 w = *(const uint2*)(Y + ((size_t)s * 4 + r) * 64 + g * 4);
        fma_bf2(w.x, 1.f, a0[0], a1[0]);
        fma_bf2(w.y, 1.f, a2[0], a3[0]);
      }
    }
    float di = dsi[(size_t)r * N_NODES + node];
    t0 = fmaf((a0[0] + a0[1]) + (a0[2] + a0[3]), di, t0);
    t1 = fmaf((a1[0] + a1[1]) + (a1[2] + a1[3]), di, t1);
    t2 = fmaf((a2[0] + a2[1]) + (a2[2] + a2[3]), di, t2);
    t3 = fmaf((a3[0] + a3[1]) + (a3[2] + a3[3]), di, t3);
  }
#pragma unroll
  for (int r = 0; r < 4; ++r) {
    float4 bb = *(const float4*)(b2 + r * 64 + g * 4);
    t0 += bb.x;
    t1 += bb.y;
    t2 += bb.z;
    t3 += bb.w;
  }
  *(float4*)(out + (size_t)node * 64 + g * 4) = make_float4(t0, t1, t2, t3);
}

extern "C" void kernel_launch(void* const* d_in, const int* in_sizes, int n_in,
                              void* d_out, int out_size, void* d_ws,
                              size_t ws_size, hipStream_t stream) {
  const float* x  = (const float*)d_in[0];
  const int* src  = (const int*)d_in[1];
  const int* dst  = (const int*)d_in[2];
  const float* W1 = (const float*)d_in[3];
  const float* b1 = (const float*)d_in[4];
  const float* W2 = (const float*)d_in[5];
  const float* b2 = (const float*)d_in[6];
  float* out = (float*)d_out;

  // Workspace layout (round-13 form):
  //   [0, 12.8MB)     Hs -- aliased by h1 bf16 (Hs dead after reduce_m)
  //   [12.8, 25.6MB)  Hd (alive until fill2m)
  //   [25.6, 38.4MB)  xb bf16 [50000][128]
  //   [38.4, 89.6MB)  agg bf16 [50000][4][128]; later Y2 [50000][4][64] alias
  //   tail: Wt1 | Wt2 | dso | dsi | relOff | cnt_m | row_ptr | chunkSums | sorted(ushort)
  char* wsb = (char*)d_ws;
  unsigned short* Hs = (unsigned short*)wsb;                 // 12.8MB
  unsigned short* h1 = (unsigned short*)wsb;                 // alias
  unsigned short* Hd = Hs + (size_t)N_REL * EB * N_NODES;    // 12.8MB
  unsigned short* xb = Hd + (size_t)N_REL * EB * N_NODES;    // 12.8MB
  unsigned short* agg = xb + (size_t)N_NODES * 128;          // 51.2MB
  unsigned short* Y2 = agg;                                  // alias
  char* tail = (char*)(agg + (size_t)N_NODES * 512);
  unsigned short* Wt1 = (unsigned short*)tail;               // 128KB
  unsigned short* Wt2 = Wt1 + 128 * 512;                     // 64KB
  float* dso = (float*)(Wt2 + 256 * 128);                    // 800KB
  float* dsi = dso + N_REL * N_NODES;                        // 800KB
  ushort4* relOff = (ushort4*)(dsi + N_REL * N_NODES);       // 400KB
  int* cnt_m = (int*)(relOff + N_NODES);                     // 200KB
  int* row_ptr = cnt_m + N_NODES;                            // 200KB
  int* chunkSums = row_ptr + (N_NODES + 1);                  // ~256B
  unsigned short* sorted = (unsigned short*)(chunkSums + 64);  // 3.2MB

  k_prep_fused<<<PX_BLOCKS + PW_BLOCKS + HIST_BLOCKS, 256, 0, stream>>>(
      x, W1, W2, src, dst, xb, Wt1, Wt2, Hs, Hd, chunkSums);
  k_reduce_m<<<(N_NODES + 255) / 256, 256, 0, stream>>>(Hs, Hd, cnt_m, dso,
                                                        dsi, relOff, chunkSums);
  k_scan_chunks<<<1, 64, 0, stream>>>(chunkSums, row_ptr);
  k_scan_within<<<NCHUNK, 256, 0, stream>>>(cnt_m, chunkSums, row_ptr);
  k_fill2m<<<N_REL * EB * NR, 256, 0, stream>>>(src, dst, Hd, row_ptr, sorted);

  // Layer 1: aggregate-first gather, then one K=512 MFMA GEMM (+bias+ReLU)
  k_gather1a<<<N_NODES / 8, 256, 0, stream>>>(xb, row_ptr, relOff, sorted, dso,
                                              dsi, (unsigned int*)agg);
  k_gemm_h1<<<(N_NODES + 63) / 64, 256, 0, stream>>>(agg, Wt1, b1, h1,
                                                     N_NODES);
  // Layer 2: transform-first GEMM into Y2 [node][4][64], then gather
  k_gemm_mfma<64><<<(N_NODES + 63) / 64, 256, 0, stream>>>(h1, Wt2, dso, Y2,
                                                           256, N_NODES);
  k_gather2m<<<N_NODES / 16, 256, 0, stream>>>(Y2, row_ptr, relOff, sorted,
                                               dsi, b2, out);
}